// Round 5
// baseline (495.871 us; speedup 1.0000x reference)
//
#include <hip/hip_runtime.h>
#include <stdint.h>

// Periodic radius-graph neighbor list (AlphaNet). B=16, N=256, C=27, M=6912.
// Outputs (flat f32 concat): dist [B,N,M], dvec [B,N,M,3], num_neighbors_image [B].
// keep = (1e-4 < dsqr <= 25) AND stable-sort rank < 32
//      == key (f32bits(dsqr)<<32 | m) among the 32 smallest within-radius keys.
//
// R14 = R13 (plain stores, reg offsets, stores->pass1->barrier) batched x4:
// 1024 blocks, each owns 4 consecutive rows (same batch b).
//  - Falsified: store deps (R10), split (R11), nt->plain won ~10% (R12),
//    barrier placement (R13 neutral). Remaining gap vs rocclr fill
//    (~4.7 vs 6.05 TB/s): per-wave store DEPTH + launch ramp/tail.
//  - Now 108 back-to-back float4 stores/thread (fill-like depth, was 27),
//    4x fewer block launches, drain barrier amortized over 4 rows of pass-1
//    (108 candidate iters overlap the drain), pos/cell loads amortized.
//  - Same bit-exact math (contract off, identical expression forms), same
//    key = (f32bits(dsq)<<32 | j*27+c), same rank/scatter per row.
// Predicted: ours ~97 -> ~85 us; total ~460 at fill~298 clocks.
// If neutral: depth/tail falsified too -> structural floor -> ROOFLINE.

constexpr int B_ = 16, N_ = 256, C_ = 27;
constexpr int M_ = N_ * C_;      // 6912
constexpr int MAXC = 256;        // candidate slots per row; mean ~78
constexpr int KMAX = 32;
constexpr int RPB  = 4;          // rows (receivers) per block

typedef float vfloat4 __attribute__((ext_vector_type(4)));

__global__ __launch_bounds__(256)
void nbr_kernel(const float* __restrict__ pos,    // [B,N,3]
                const float* __restrict__ cell,   // [B,3,3]
                float* __restrict__ dist,         // [B,N,M]
                float* __restrict__ dvec,         // [B,N,M,3]
                float* __restrict__ nn)           // [B] (float counts, pre-zeroed)
{
#pragma clang fp contract(off)
    __shared__ unsigned long long keys[RPB][MAXC];
    __shared__ float4 vals[RPB][MAXC];           // dx,dy,dz,dsq
    __shared__ float4 kept[RPB][KMAX];           // dx,dy,dz,dist (by rank)
    __shared__ int    keptm[RPB][KMAX];          // candidate index m (by rank)
    __shared__ int    cnt[RPB];

    const int blk = blockIdx.x;                  // 0..1023
    const int tid = threadIdx.x;
    const int b   = blk >> 6;                    // batch (same for all 4 rows)
    const int i0  = (blk & 63) * RPB;            // first receiver index

    // ---- barrier while nothing is in flight: publish cnt[]=0.
    if (tid < RPB) cnt[tid] = 0;
    __syncthreads();

    // ---- loads first (so their waitcnt doesn't imply store drain).
    const float* pb = pos + b * N_ * 3;
    const float pjx = pb[tid * 3 + 0], pjy = pb[tid * 3 + 1], pjz = pb[tid * 3 + 2];
    const float* cb = cell + b * 9;
    const float c0 = cb[0], c1 = cb[1], c2 = cb[2];
    const float c3 = cb[3], c4 = cb[4], c5 = cb[5];
    const float c6 = cb[6], c7 = cb[7], c8 = cb[8];

    // Block's 4 rows are contiguous in both regions:
    float* drow0 = dist + (size_t)(blk * RPB) * M_;                 // 27648 f
    float* vrow0 = dvec + (size_t)(blk * RPB) * (size_t)(M_ * 3);   // 82944 f

    // ---- phase A: zero stream, plain stores, 108 back-to-back per thread.
    // dist region: 4*1728 = 6912 groups = 27*256 ; dvec: 20736 = 81*256.
    {
        vfloat4 z; z.x = 0.f; z.y = 0.f; z.z = 0.f; z.w = 0.f;
        #pragma unroll
        for (int k = 0; k < 27; ++k)
            *(vfloat4*)(drow0 + 4 * (tid + k * 256)) = z;
        #pragma unroll
        for (int k = 0; k < 81; ++k)
            *(vfloat4*)(vrow0 + 4 * (tid + k * 256)) = z;
    }

    // ---- phase B1: pass 1 for 4 rows (regs + LDS atomics only; overlaps
    // the store drain). Bit-exact numpy order: off = n1*cb[0]+n2*cb[3]+
    // n3*cb[6] etc; s = pj + off; d = pi - s; ((dx*dx+dy*dy)+dz*dz).
    #pragma unroll 1
    for (int it = 0; it < RPB; ++it) {
        const int ii = i0 + it;
        const float pix = pb[ii * 3 + 0], piy = pb[ii * 3 + 1], piz = pb[ii * 3 + 2];
        #pragma unroll 1
        for (int c = 0; c < C_; ++c) {
            const float n1 = (float)(c / 9 - 1);
            const float n2 = (float)((c / 3) % 3 - 1);
            const float n3 = (float)(c % 3 - 1);
            const float ox = n1 * c0 + n2 * c3 + n3 * c6;
            const float oy = n1 * c1 + n2 * c4 + n3 * c7;
            const float oz = n1 * c2 + n2 * c5 + n3 * c8;
            const float sx = pjx + ox, sy = pjy + oy, sz = pjz + oz;
            const float dx = pix - sx, dy = piy - sy, dz = piz - sz;
            const float dsq = dx * dx + dy * dy + dz * dz;
            if (dsq <= 25.0f && dsq > 1e-4f) {
                const int idx = atomicAdd(&cnt[it], 1);          // LDS atomic
                if (idx < MAXC) {
                    keys[it][idx] = ((unsigned long long)__float_as_uint(dsq) << 32)
                                  | (unsigned)(tid * C_ + c);
                    vals[it][idx] = make_float4(dx, dy, dz, dsq);
                }
            }
        }
    }
    __syncthreads();   // drains stores too - overlapped with all of B1 above

    // ---- nn: one atomic per block (sum of min(K,32) over 4 rows; exact in f32)
    if (tid == 0) {
        int s = 0;
        #pragma unroll
        for (int it = 0; it < RPB; ++it) {
            int K = cnt[it]; if (K > MAXC) K = MAXC;
            s += (K < KMAX ? K : KMAX);
        }
        atomicAdd(&nn[b], (float)s);
    }

    // ---- phase B2: ranking -> compact kept list per row (keys unique since
    // m unique; each rank r in [0,nk) written exactly once).
    #pragma unroll 1
    for (int it = 0; it < RPB; ++it) {
        int K = cnt[it]; if (K > MAXC) K = MAXC;
        for (int idx = tid; idx < K; idx += 256) {
            const unsigned long long key = keys[it][idx];
            int r = 0;
            for (int q = 0; q < K; ++q) r += (keys[it][q] < key) ? 1 : 0;
            if (r < KMAX) {
                const float4 v = vals[it][idx];
                kept[it][r]  = make_float4(v.x, v.y, v.z, sqrtf(v.w));
                keptm[it][r] = (int)(key & 0xffffffffu);
            }
        }
    }

    // ---- phase C: barrier orders phase-A zero stores before fix-up stores;
    // zero lines still dirty in L2 so the scatter merges there (no HBM RMW).
    __syncthreads();

    #pragma unroll 1
    for (int it = 0; it < RPB; ++it) {
        int K = cnt[it]; if (K > MAXC) K = MAXC;
        const int nk = K < KMAX ? K : KMAX;
        if (tid < nk) {
            const float4 v = kept[it][tid];
            const int m = keptm[it][tid];
            float* drow = drow0 + (size_t)it * M_;
            float* vp   = vrow0 + (size_t)it * (size_t)(M_ * 3) + 3 * m;
            drow[m] = v.w;
            vp[0] = v.x;
            vp[1] = v.y;
            vp[2] = v.z;
        }
    }
}

extern "C" void kernel_launch(void* const* d_in, const int* in_sizes, int n_in,
                              void* d_out, int out_size, void* d_ws, size_t ws_size,
                              hipStream_t stream)
{
    const float* pos  = (const float*)d_in[0];
    const float* cell = (const float*)d_in[1];
    float* dist = (float*)d_out;
    float* dvec = dist + (size_t)B_ * N_ * M_;
    float* nn   = dvec + (size_t)B_ * N_ * M_ * 3;
    (void)hipMemsetAsync(nn, 0, B_ * sizeof(float), stream);   // zero count tail only
    nbr_kernel<<<dim3(B_ * N_ / RPB), dim3(256), 0, stream>>>(pos, cell, dist, dvec, nn);
}

// Round 6
// 471.293 us; speedup vs baseline: 1.0522x; 1.0522x over previous
//
#include <hip/hip_runtime.h>
#include <stdint.h>

// Periodic radius-graph neighbor list (AlphaNet). B=16, N=256, C=27, M=6912.
// Outputs (flat f32 concat): dist [B,N,M], dvec [B,N,M,3], num_neighbors_image [B].
// keep = (1e-4 < dsqr <= 25) AND stable-sort rank < 32
//      == key (f32bits(dsqr)<<32 | m) among the 32 smallest within-radius keys.
//
// R15 = revert to R13 (best verified: 472 us @ fill~298 clocks, ours ~97 us).
// Optimization history on the write stream (453 MB, the only real traffic):
//  - R10: dependency-free zero stream == gather-merged stream (deps NOT the
//    throttle).
//  - R11: separate rocclr-shaped fill kernel + compute kernel: +66 us (split
//    serialization; the "pure" fill STILL ran at ~4.7 TB/s, not 6.05).
//  - R12: nontemporal -> plain cached stores: ~10% WIN (L2 write-combining
//    path; nt bypass was a real tax). Kept.
//  - R13: stores -> pass1 -> barrier (drain overlapped with compute): neutral
//    (inter-block overlap already hid the drain). Kept (harmless, tidier).
//  - R14: 4 rows/block, 108 stores/thread fill-like depth: -20 us REGRESSION
//    (LDS 6.6->27 KB cut blocks/CU 8->5; less inter-block MLP). Reverted.
// Conclusion: ~4.7 TB/s effective for a compute-bearing kernel vs 6.05 for
// the dedicated fill is structural on gfx950; every lever (deps, split, nt,
// barriers, depth) has been isolated and tested. This is the floor:
// poison ~376 + fill 453MB@4.7 ~97 us.

constexpr int B_ = 16, N_ = 256, C_ = 27;
constexpr int M_ = N_ * C_;      // 6912
constexpr int MAXC = 256;        // candidate slots; mean ~78, 20-sigma safe
constexpr int KMAX = 32;

typedef float vfloat4 __attribute__((ext_vector_type(4)));

__global__ __launch_bounds__(256)
void nbr_kernel(const float* __restrict__ pos,    // [B,N,3]
                const float* __restrict__ cell,   // [B,3,3]
                float* __restrict__ dist,         // [B,N,M]
                float* __restrict__ dvec,         // [B,N,M,3]
                float* __restrict__ nn)           // [B] (float counts, pre-zeroed)
{
#pragma clang fp contract(off)
    __shared__ unsigned long long keys[MAXC];
    __shared__ float4 vals[MAXC];               // dx,dy,dz,dsq
    __shared__ float4 kept[KMAX];               // dx,dy,dz,dist (by rank)
    __shared__ int    keptm[KMAX];              // candidate index m (by rank)
    __shared__ int cnt;

    const int bi  = blockIdx.x;   // b*N + i
    const int b   = bi >> 8;
    const int i   = bi & 255;
    const int tid = threadIdx.x;

    // ---- barrier while nothing is in flight: publish cnt=0.
    if (tid == 0) cnt = 0;
    __syncthreads();

    // ---- loads first (so their waitcnt doesn't imply store drain).
    const float* pb = pos + b * N_ * 3;
    const float pjx = pb[tid * 3 + 0], pjy = pb[tid * 3 + 1], pjz = pb[tid * 3 + 2];
    const float pix = pb[i * 3 + 0],   piy = pb[i * 3 + 1],   piz = pb[i * 3 + 2];
    const float* cb = cell + b * 9;
    const float c0 = cb[0], c1 = cb[1], c2 = cb[2];
    const float c3 = cb[3], c4 = cb[4], c5 = cb[5];
    const float c6 = cb[6], c7 = cb[7], c8 = cb[8];

    float* drow = dist + (size_t)bi * M_;
    float* vrow = dvec + (size_t)bi * (size_t)(M_ * 3);

    // ---- phase A: zero stream, plain stores (L2 write-combining path).
    // dist row: 1728 float4 = 6*256 + 192 ; dvec row: 5184 float4 = 20*256 + 64.
    {
        vfloat4 z; z.x = 0.f; z.y = 0.f; z.z = 0.f; z.w = 0.f;
        #pragma unroll
        for (int k = 0; k < 6; ++k)
            *(vfloat4*)(drow + 4 * (tid + k * 256)) = z;
        if (tid < 192)
            *(vfloat4*)(drow + 4 * (1536 + tid)) = z;
        #pragma unroll
        for (int k = 0; k < 20; ++k)
            *(vfloat4*)(vrow + 4 * (tid + k * 256)) = z;
        if (tid < 64)
            *(vfloat4*)(vrow + 4 * (5120 + tid)) = z;
    }

    // ---- phase B1 (runs while stores drain; regs + LDS atomics only).
    // Bit-exact numpy order: off = n1*cb[0]+n2*cb[3]+n3*cb[6] etc (contract
    // off); s = pj + off; d = pi - s; ((dx*dx+dy*dy)+dz*dz).
    #pragma unroll 1
    for (int c = 0; c < C_; ++c) {
        const float n1 = (float)(c / 9 - 1);
        const float n2 = (float)((c / 3) % 3 - 1);
        const float n3 = (float)(c % 3 - 1);
        const float ox = n1 * c0 + n2 * c3 + n3 * c6;
        const float oy = n1 * c1 + n2 * c4 + n3 * c7;
        const float oz = n1 * c2 + n2 * c5 + n3 * c8;
        const float sx = pjx + ox, sy = pjy + oy, sz = pjz + oz;
        const float dx = pix - sx, dy = piy - sy, dz = piz - sz;
        const float dsq = dx * dx + dy * dy + dz * dz;
        if (dsq <= 25.0f && dsq > 1e-4f) {
            const int idx = atomicAdd(&cnt, 1);              // LDS atomic
            if (idx < MAXC) {
                keys[idx] = ((unsigned long long)__float_as_uint(dsq) << 32)
                          | (unsigned)(tid * C_ + c);
                vals[idx] = make_float4(dx, dy, dz, dsq);
            }
        }
    }
    __syncthreads();   // drains stores too - overlapped with all of B1 above

    int K = cnt; if (K > MAXC) K = MAXC;
    const int nk = K < KMAX ? K : KMAX;
    if (tid == 0)
        atomicAdd(&nn[b], (float)nk);

    // ---- phase B2: ranking -> compact kept list (keys unique since m unique;
    // each rank r in [0,nk) written exactly once).
    for (int idx = tid; idx < K; idx += 256) {
        const unsigned long long key = keys[idx];
        int r = 0;
        for (int q = 0; q < K; ++q) r += (keys[q] < key) ? 1 : 0;
        if (r < KMAX) {
            const float4 v = vals[idx];
            kept[r]  = make_float4(v.x, v.y, v.z, sqrtf(v.w));
            keptm[r] = (int)(key & 0xffffffffu);
        }
    }

    // ---- phase C: barrier orders phase-A zero stores before fix-up stores;
    // zero lines still dirty in L2 so the scatter merges there (no HBM RMW).
    __syncthreads();

    if (tid < nk) {
        const float4 v = kept[tid];
        const int m = keptm[tid];
        drow[m]         = v.w;      // dist
        float* vp = vrow + 3 * m;   // dvec
        vp[0] = v.x;
        vp[1] = v.y;
        vp[2] = v.z;
    }
}

extern "C" void kernel_launch(void* const* d_in, const int* in_sizes, int n_in,
                              void* d_out, int out_size, void* d_ws, size_t ws_size,
                              hipStream_t stream)
{
    const float* pos  = (const float*)d_in[0];
    const float* cell = (const float*)d_in[1];
    float* dist = (float*)d_out;
    float* dvec = dist + (size_t)B_ * N_ * M_;
    float* nn   = dvec + (size_t)B_ * N_ * M_ * 3;
    (void)hipMemsetAsync(nn, 0, B_ * sizeof(float), stream);   // zero count tail only
    nbr_kernel<<<dim3(B_ * N_), dim3(256), 0, stream>>>(pos, cell, dist, dvec, nn);
}